// Round 2
// baseline (3373.019 us; speedup 1.0000x reference)
//
#include <hip/hip_runtime.h>

#define C   64
#define H   128
#define W   128
#define HW  (H * W)
#define NB  8
#define NPIX (NB * H * W)      // 131072 pixels
#define THREADS 256

// Fused: h = conv3x3(y,w1)+b1 kept in registers; per-pixel dynamic kernel
// ker[c,t] = w2[c*9+t,:]·h + b2 computed on the fly and contracted with the
// 3x3 x-patch. The (N,576,H,W) kernel tensor is never materialized.
//
// Thread = one pixel (n,p,q), owns all 64 channels.
// LDS = weight chunk (16 output channels at a time), wave-uniform broadcast
// reads, w1 rows padded 9->12 floats for 16B-aligned float4 reads.
__global__ __launch_bounds__(THREADS) void fused_dc3x3(
    const float* __restrict__ x,
    const float* __restrict__ y,
    const float* __restrict__ w1,
    const float* __restrict__ b1,
    const float* __restrict__ w2,
    const float* __restrict__ b2,
    float* __restrict__ out)
{
    __shared__ __align__(16) float wlds[12288];   // 48 KB

    const int pix  = blockIdx.x * THREADS + threadIdx.x;
    const int n    = pix >> 14;          // NB=8
    const int prow = pix & (HW - 1);     // p*W + q
    const int p    = prow >> 7;
    const int q    = prow & (W - 1);

    // 3x3 tap geometry, shared by the y-conv and the x-unfold (same padding)
    int  offc[9];
    bool okb[9];
    #pragma unroll
    for (int t = 0; t < 9; ++t) {
        int hh = p + t / 3 - 1;
        int ww = q + t % 3 - 1;
        bool ok = ((unsigned)hh < (unsigned)H) && ((unsigned)ww < (unsigned)W);
        okb[t]  = ok;
        offc[t] = ok ? hh * W + ww : 0;  // clamped -> load always in-bounds
    }

    const float* ybase = y + (size_t)n * C * HW;

    float hv[C];
    #pragma unroll
    for (int i = 0; i < C; ++i) hv[i] = 0.0f;

    // ---------------- phase 1: hv = conv3x3(y, w1) ----------------
    // chunk = 16 output channels; LDS layout [co16][k64][12] (9 taps padded
    // to 12 -> every (co,k) row 16B-aligned => ds_read_b128)
    #pragma unroll
    for (int cb = 0; cb < 4; ++cb) {
        const float* wsrc = w1 + cb * (16 * C * 9);
        for (int i = threadIdx.x; i < 16 * C * 9; i += THREADS) {
            int co = i / 576;
            int r  = i - co * 576;
            int k  = r / 9;
            int tp = r - k * 9;
            wlds[(co * 64 + k) * 12 + tp] = wsrc[i];
        }
        __syncthreads();
        for (int k = 0; k < C; ++k) {
            const float* yk = ybase + k * HW;
            float yv[9];
            #pragma unroll
            for (int t = 0; t < 9; ++t)
                yv[t] = okb[t] ? yk[offc[t]] : 0.0f;
            #pragma unroll
            for (int cl = 0; cl < 16; ++cl) {
                const float* row = &wlds[(cl * 64 + k) * 12];
                float4 wa = *(const float4*)row;
                float4 wb = *(const float4*)(row + 4);
                float  w8 = row[8];
                float s = hv[cb * 16 + cl];
                s = fmaf(wa.x, yv[0], s);
                s = fmaf(wa.y, yv[1], s);
                s = fmaf(wa.z, yv[2], s);
                s = fmaf(wa.w, yv[3], s);
                s = fmaf(wb.x, yv[4], s);
                s = fmaf(wb.y, yv[5], s);
                s = fmaf(wb.z, yv[6], s);
                s = fmaf(wb.w, yv[7], s);
                s = fmaf(w8,   yv[8], s);
                hv[cb * 16 + cl] = s;
            }
        }
        __syncthreads();
    }

    #pragma unroll
    for (int i = 0; i < C; ++i) hv[i] += b1[i];

    // ---------------- phase 2: dynamic conv ----------------
    // chunk = 16 output channels = 144 w2 rows of 64 floats (raw copy, rows
    // contiguous -> float4 LDS reads, broadcast across the wave)
    for (int cb = 0; cb < 4; ++cb) {
        const float* wsrc = w2 + cb * (16 * 9 * C);
        for (int i = threadIdx.x; i < 16 * 9 * C; i += THREADS)
            wlds[i] = wsrc[i];
        __syncthreads();
        for (int cl = 0; cl < 16; ++cl) {
            int cc = cb * 16 + cl;
            const float* xc   = x + ((size_t)n * C + cc) * HW;
            const float* brow = b2 + cc * 9;
            float acc = 0.0f;
            #pragma unroll
            for (int t = 0; t < 9; ++t) {
                const float4* row4 = (const float4*)&wlds[(cl * 9 + t) * 64];
                float k0 = 0.0f, k1 = 0.0f, k2 = 0.0f, k3 = 0.0f;
                #pragma unroll
                for (int kq = 0; kq < 16; ++kq) {
                    float4 wv = row4[kq];
                    k0 = fmaf(wv.x, hv[4 * kq + 0], k0);
                    k1 = fmaf(wv.y, hv[4 * kq + 1], k1);
                    k2 = fmaf(wv.z, hv[4 * kq + 2], k2);
                    k3 = fmaf(wv.w, hv[4 * kq + 3], k3);
                }
                float ker = brow[t] + ((k0 + k1) + (k2 + k3));
                float xv  = okb[t] ? xc[offc[t]] : 0.0f;
                acc = fmaf(ker, xv, acc);
            }
            out[((size_t)n * C + cc) * HW + prow] = acc;
        }
        __syncthreads();
    }
}

extern "C" void kernel_launch(void* const* d_in, const int* in_sizes, int n_in,
                              void* d_out, int out_size, void* d_ws, size_t ws_size,
                              hipStream_t stream)
{
    const float* x  = (const float*)d_in[0];
    const float* y  = (const float*)d_in[1];
    const float* w1 = (const float*)d_in[2];
    const float* b1 = (const float*)d_in[3];
    const float* w2 = (const float*)d_in[4];
    const float* b2 = (const float*)d_in[5];
    float* out = (float*)d_out;

    fused_dc3x3<<<NPIX / THREADS, THREADS, 0, stream>>>(x, y, w1, b1, w2, b2, out);
}

// Round 3
// 149.588 us; speedup vs baseline: 22.5488x; 22.5488x over previous
//
#include <hip/hip_runtime.h>

#define C   64
#define H   128
#define W   128
#define HW  (H * W)
#define NB  8

using bf16x8 = __attribute__((ext_vector_type(8))) short;
using f32x4  = __attribute__((ext_vector_type(4))) float;

__device__ __forceinline__ unsigned short f2bf(float f) {
    unsigned u = __float_as_uint(f);
    return (unsigned short)((u + 0x7fffu + ((u >> 16) & 1u)) >> 16);
}

// ---------------------------------------------------------------------------
// Prep: permute weights into MFMA-friendly layouts (bf16) + permuted b2 (f32)
//   w1p[co][kk],  kk = tap*64 + k   <- w1[co][k][tap]
//   w2p[m'][k],   m' = tap*64 + c   <- w2[c*9+tap][k]
//   b2p[m']                          <- b2[c*9+tap]
// ---------------------------------------------------------------------------
__global__ __launch_bounds__(256) void prep_weights(
    const float* __restrict__ w1, const float* __restrict__ w2,
    const float* __restrict__ b2,
    unsigned short* __restrict__ w1p, unsigned short* __restrict__ w2p,
    float* __restrict__ b2p)
{
    int i = blockIdx.x * 256 + threadIdx.x;
    if (i < 36864) {
        int co = i / 576, rem = i % 576, tap = rem >> 6, k = rem & 63;
        w1p[i] = f2bf(w1[co * 576 + k * 9 + tap]);
    }
    if (i < 36864) {
        int mp = i >> 6, k = i & 63, tap = mp >> 6, c = mp & 63;
        w2p[i] = f2bf(w2[(c * 9 + tap) * 64 + k]);
    }
    if (i < 576) {
        int tap = i >> 6, c = i & 63;
        b2p[i] = b2[c * 9 + tap];
    }
}

// ---------------------------------------------------------------------------
// Kernel 1: h^T[n][pix][co] (bf16, +b1) = conv3x3(y, w1)
// Implicit GEMM: C[pix][co] = A(y patches)[pix][kk] * B(w1^T)[kk][co]
// Block = 1 image row (128 px), 2 waves (64 px each). y row-tile in LDS.
// ---------------------------------------------------------------------------
__global__ __launch_bounds__(128) void dc_conv3x3(
    const float* __restrict__ y,
    const unsigned short* __restrict__ w1p,
    const float* __restrict__ b1,
    unsigned short* __restrict__ hT)
{
    __shared__ unsigned short ylds[3 * 130 * 64];   // 48.75 KB, [row][col][k] swizzled

    const int t = threadIdx.x;
    const int b = blockIdx.x;
    const int n = b >> 7, p = b & 127;

    // ---- stage y rows p-1..p+1 (cols padded ±1, zeros) as bf16, k-swizzled
    {
        int col = 1 + t;                               // 1..128 -> gcol = t
        const float* ysrc = y + (size_t)n * C * HW + t;
        #pragma unroll
        for (int row = 0; row < 3; ++row) {
            int grow = p - 1 + row;
            bool rok = (unsigned)grow < (unsigned)H;
            const float* yr = ysrc + (size_t)grow * W;
            for (int kp = 0; kp < 32; ++kp) {
                int k0 = kp * 2;
                float v0 = rok ? yr[(size_t)k0 * HW] : 0.0f;
                float v1 = rok ? yr[(size_t)(k0 + 1) * HW] : 0.0f;
                unsigned pk = (unsigned)f2bf(v0) | ((unsigned)f2bf(v1) << 16);
                int idx = (row * 130 + col) * 64 + (((k0 >> 3) ^ (col & 7)) << 3) + (k0 & 7);
                *(unsigned*)&ylds[idx] = pk;
            }
        }
        // zero halo columns 0 and 129
        for (int i = t; i < 192; i += 128) {
            int row = i >> 6, rem = i & 63;
            int ecol = (rem >> 5) ? 129 : 0;
            int k0 = (rem & 31) * 2;
            int idx = (row * 130 + ecol) * 64 + (((k0 >> 3) ^ (ecol & 7)) << 3) + (k0 & 7);
            *(unsigned*)&ylds[idx] = 0u;
        }
    }
    __syncthreads();

    const int wid = t >> 6, lane = t & 63;
    const int l15 = lane & 15, lhi = lane >> 4;
    const int q0 = wid << 6;

    f32x4 acc[4][4];
    #pragma unroll
    for (int m = 0; m < 4; ++m)
        #pragma unroll
        for (int pt = 0; pt < 4; ++pt)
            acc[m][pt] = f32x4{0.f, 0.f, 0.f, 0.f};

    for (int s = 0; s < 18; ++s) {
        int tap = s >> 1;
        int trow = tap / 3;               // 0..2 -> y row p-1+trow
        int dq = tap % 3 - 1;
        int k0 = (s & 1) * 32 + lhi * 8;

        bf16x8 Y[4];
        #pragma unroll
        for (int pt = 0; pt < 4; ++pt) {
            int colt = 1 + q0 + pt * 16 + l15 + dq;
            int idx = (trow * 130 + colt) * 64 + (((k0 >> 3) ^ (colt & 7)) << 3);
            Y[pt] = *(const bf16x8*)&ylds[idx];
        }
        int kk = s * 32 + lhi * 8;
        bf16x8 Wf[4];
        #pragma unroll
        for (int m = 0; m < 4; ++m)
            Wf[m] = *(const bf16x8*)&w1p[(m * 16 + l15) * 576 + kk];

        #pragma unroll
        for (int m = 0; m < 4; ++m)
            #pragma unroll
            for (int pt = 0; pt < 4; ++pt)
                acc[m][pt] = __builtin_amdgcn_mfma_f32_16x16x32_bf16(
                    Y[pt], Wf[m], acc[m][pt], 0, 0, 0);
    }

    // epilogue: +b1, cvt bf16, store h^T[pix][co]
    #pragma unroll
    for (int m = 0; m < 4; ++m) {
        float bsp = b1[m * 16 + l15];
        #pragma unroll
        for (int pt = 0; pt < 4; ++pt) {
            int pixb = p * W + q0 + pt * 16 + lhi * 4;
            #pragma unroll
            for (int r = 0; r < 4; ++r) {
                float v = acc[m][pt][r] + bsp;
                hT[((size_t)n * HW + pixb + r) * 64 + m * 16 + l15] = f2bf(v);
            }
        }
    }
}

// ---------------------------------------------------------------------------
// Kernel 2: fused 1x1-conv (-> per-pixel 9-tap kernel) + dynamic conv.
// C[pix][m'] = h^T[pix][k] * w2p^T[k][m'] (+b2), m' = tap*64 + c;
// out[c][pix] = sum_tap kernel[m'][pix] * x[c][pix+off_tap]  (x stays f32)
// Block = 2 image rows, 4 waves (64 px each). No LDS.
// ---------------------------------------------------------------------------
__global__ __launch_bounds__(256) void dc_dyn(
    const float* __restrict__ x,
    const unsigned short* __restrict__ hT,
    const unsigned short* __restrict__ w2p,
    const float* __restrict__ b2p,
    float* __restrict__ out)
{
    const int t = threadIdx.x, b = blockIdx.x;
    const int n = b >> 6;
    const int wid = t >> 6, lane = t & 63;
    const int l15 = lane & 15, lhi = lane >> 4;
    const int p = ((b & 63) << 1) + (wid >> 1);
    const int q0 = (wid & 1) << 6;

    // preload h fragments (A operand; reused for all 36 (tap,cc) tiles)
    bf16x8 hA[4][2];
    #pragma unroll
    for (int pt = 0; pt < 4; ++pt)
        #pragma unroll
        for (int ks = 0; ks < 2; ++ks)
            hA[pt][ks] = *(const bf16x8*)&hT[
                ((size_t)n * HW + p * W + q0 + pt * 16 + l15) * 64 + ks * 32 + lhi * 8];

    for (int cc = 0; cc < 4; ++cc) {
        const int c = cc * 16 + l15;                 // this lane's output channel
        const float* xc = x + ((size_t)n * C + c) * HW;

        #pragma unroll
        for (int pp = 0; pp < 2; ++pp) {
            float xn[2][3][6];
            f32x4 oacc[2];
            #pragma unroll
            for (int e = 0; e < 2; ++e) {
                oacc[e] = f32x4{0.f, 0.f, 0.f, 0.f};
                int pt = pp * 2 + e;
                int cb = q0 + pt * 16 + lhi * 4;     // 16B-aligned col base
                #pragma unroll
                for (int ri = 0; ri < 3; ++ri) {
                    int grow = p - 1 + ri;           // wave-uniform
                    if ((unsigned)grow < (unsigned)H) {
                        const float* xr = xc + (size_t)grow * W;
                        float4 mid = *(const float4*)&xr[cb];
                        xn[e][ri][1] = mid.x; xn[e][ri][2] = mid.y;
                        xn[e][ri][3] = mid.z; xn[e][ri][4] = mid.w;
                        xn[e][ri][0] = (cb > 0)        ? xr[cb - 1] : 0.f;
                        xn[e][ri][5] = (cb + 4 <= 127) ? xr[cb + 4] : 0.f;
                    } else {
                        #pragma unroll
                        for (int cj = 0; cj < 6; ++cj) xn[e][ri][cj] = 0.f;
                    }
                }
            }

            #pragma unroll
            for (int tap = 0; tap < 9; ++tap) {
                const unsigned short* w2r = &w2p[(tap * 64 + cc * 16 + l15) * 64 + lhi * 8];
                bf16x8 w2f0 = *(const bf16x8*)&w2r[0];
                bf16x8 w2f1 = *(const bf16x8*)&w2r[32];
                float bv = b2p[tap * 64 + cc * 16 + l15];
                f32x4 binit = {bv, bv, bv, bv};
                int ri = tap / 3, cj = tap % 3;
                #pragma unroll
                for (int e = 0; e < 2; ++e) {
                    int pt = pp * 2 + e;
                    f32x4 kf = __builtin_amdgcn_mfma_f32_16x16x32_bf16(
                        hA[pt][0], w2f0, binit, 0, 0, 0);
                    kf = __builtin_amdgcn_mfma_f32_16x16x32_bf16(
                        hA[pt][1], w2f1, kf, 0, 0, 0);
                    #pragma unroll
                    for (int r = 0; r < 4; ++r)
                        oacc[e][r] = fmaf(kf[r], xn[e][ri][r + cj], oacc[e][r]);
                }
            }

            #pragma unroll
            for (int e = 0; e < 2; ++e) {
                int pt = pp * 2 + e;
                float* dst = out + ((size_t)n * C + c) * HW
                           + (size_t)p * W + q0 + pt * 16 + lhi * 4;
                *(f32x4*)dst = oacc[e];
            }
        }
    }
}

extern "C" void kernel_launch(void* const* d_in, const int* in_sizes, int n_in,
                              void* d_out, int out_size, void* d_ws, size_t ws_size,
                              hipStream_t stream)
{
    const float* x  = (const float*)d_in[0];
    const float* y  = (const float*)d_in[1];
    const float* w1 = (const float*)d_in[2];
    const float* b1 = (const float*)d_in[3];
    const float* w2 = (const float*)d_in[4];
    const float* b2 = (const float*)d_in[5];
    float* out = (float*)d_out;

    char* ws = (char*)d_ws;
    unsigned short* hT  = (unsigned short*)ws;                       // 16,777,216 B
    unsigned short* w1p = (unsigned short*)(ws + 16777216);          // 73,728 B
    unsigned short* w2p = (unsigned short*)(ws + 16777216 + 73728);  // 73,728 B
    float*          b2p = (float*)(ws + 16777216 + 147456);          // 2,304 B

    prep_weights<<<144, 256, 0, stream>>>(w1, w2, b2, w1p, w2p, b2p);
    dc_conv3x3<<<NB * H, 128, 0, stream>>>(y, w1p, b1, hT);
    dc_dyn<<<NB * H / 2, 256, 0, stream>>>(x, hT, w2p, b2p, out);
}